// Round 13
// baseline (239.095 us; speedup 1.0000x reference)
//
#include <hip/hip_runtime.h>

#define NB 32768
#define NF 256
#define H1 16
#define H2 8
#define ROWS_PER_BLOCK 1024
#define ITERS (ROWS_PER_BLOCK / 64)   // 16 (one row per lane per iter)
#define FPB 4                         // features (waves) per block
#define NT (FPB * 64)                 // 256 threads

__device__ __forceinline__ float elu_f(float v) {
    return v > 0.0f ? v : (__expf(v) - 1.0f);
}
// force a wave-uniform float into an SGPR
__device__ __forceinline__ float rfl(float v) {
    return __int_as_float(__builtin_amdgcn_readfirstlane(__float_as_int(v)));
}

// R12 skeleton (coalesced x/z via LDS transpose, W2 split SGPR/LDS/VGPR) plus
// CROSS-ROW SOFTWARE PIPELINING: row i's L2-FMA consumes h1c[h] while the same
// slot is overwritten with row i+1's ELU. Every v_exp (8cyc trans pipe) is
// co-scheduled with 8 v_fma (16cyc VALU pipe) -> both pipes loaded
// simultaneously instead of alternately (the duty-cycle gap R6-R12 shared).
// No h1 copy, no second array: consume-then-overwrite per h. +16 VGPRs only.
__global__ __launch_bounds__(NT, 5)
void z_kernel(const float* __restrict__ x,  const float* __restrict__ W1,
              const float* __restrict__ b1, const float* __restrict__ W2,
              const float* __restrict__ b2, const float* __restrict__ W3,
              const float* __restrict__ b3, float* __restrict__ z_out) {
    const int wave = threadIdx.x >> 6;
    const int lane = threadIdx.x & 63;
    const int f0   = blockIdx.y * FPB;
    const int f    = f0 + wave;
    const int rowBase = blockIdx.x * ROWS_PER_BLOCK;

    __shared__ float lds_w2[FPB][32];        // W2 rows 8..11 per feature
    __shared__ float xbuf[2][FPB][64];       // [slab-buf][feat-col][row]
    __shared__ float zbuf[2][64][5];         // [buf][row][feat-col + pad]

    // ---- stage W2 rows 8..11 into LDS (8 lanes x float4) ----
    if (lane < 8) {
        const float4 v = reinterpret_cast<const float4*>(W2 + f * H1 * H2 + 64)[lane];
        reinterpret_cast<float4*>(lds_w2[wave])[lane] = v;
    }

    // ---- W2 rows 0..7 -> SGPR ----
    float s_w2[8 * H2];
    {
        const float4* p = reinterpret_cast<const float4*>(W2 + f * H1 * H2);
        #pragma unroll
        for (int i = 0; i < 16; ++i) {
            float4 v = p[i];
            s_w2[4*i]   = rfl(v.x); s_w2[4*i+1] = rfl(v.y);
            s_w2[4*i+2] = rfl(v.z); s_w2[4*i+3] = rfl(v.w);
        }
    }
    // ---- W2 rows 12..15 -> per-lane VGPR (32 floats) ----
    float w2v[32];
    {
        const float4* p = reinterpret_cast<const float4*>(W2 + f * H1 * H2 + 96);
        #pragma unroll
        for (int i = 0; i < 8; ++i) {
            float4 v = p[i];
            w2v[4*i]=v.x; w2v[4*i+1]=v.y; w2v[4*i+2]=v.z; w2v[4*i+3]=v.w;
        }
    }
    // ---- W1 -> per-lane VGPR, b1 -> SGPR ----
    float w1v[H1], s_b1[H1];
    {
        const float4* pw = reinterpret_cast<const float4*>(W1 + f * H1);
        const float4* pb = reinterpret_cast<const float4*>(b1 + f * H1);
        #pragma unroll
        for (int i = 0; i < 4; ++i) {
            float4 v = pw[i];
            w1v[4*i] = v.x; w1v[4*i+1] = v.y; w1v[4*i+2] = v.z; w1v[4*i+3] = v.w;
        }
        #pragma unroll
        for (int i = 0; i < 4; ++i) {
            float4 v = pb[i];
            s_b1[4*i]   = rfl(v.x); s_b1[4*i+1] = rfl(v.y);
            s_b1[4*i+2] = rfl(v.z); s_b1[4*i+3] = rfl(v.w);
        }
    }
    // ---- b2 -> per-lane VGPR; W3, b3 -> SGPR ----
    float b2v[H2];
    {
        const float4* p = reinterpret_cast<const float4*>(b2 + f * H2);
        float4 v0 = p[0], v1 = p[1];
        b2v[0]=v0.x; b2v[1]=v0.y; b2v[2]=v0.z; b2v[3]=v0.w;
        b2v[4]=v1.x; b2v[5]=v1.y; b2v[6]=v1.z; b2v[7]=v1.w;
    }
    float s_w3[H2];
    {
        const float4* p = reinterpret_cast<const float4*>(W3 + f * H2);
        float4 v0 = p[0], v1 = p[1];
        s_w3[0]=rfl(v0.x); s_w3[1]=rfl(v0.y); s_w3[2]=rfl(v0.z); s_w3[3]=rfl(v0.w);
        s_w3[4]=rfl(v1.x); s_w3[5]=rfl(v1.y); s_w3[6]=rfl(v1.z); s_w3[7]=rfl(v1.w);
    }
    const float s_b3 = rfl(b3[f]);

    // ---- prologue: stage x slabs 0 and 1 ----
    const int r16 = (lane & 15);
    const bool io = (lane < 16);
    const int myrow = wave * 16 + r16;           // 0..63 across the block
    if (io) {
        const float4 v0 = *reinterpret_cast<const float4*>(
            x + (size_t)(rowBase + myrow) * NF + f0);
        xbuf[0][0][myrow] = v0.x; xbuf[0][1][myrow] = v0.y;
        xbuf[0][2][myrow] = v0.z; xbuf[0][3][myrow] = v0.w;
        const float4 v1 = *reinterpret_cast<const float4*>(
            x + (size_t)(rowBase + 64 + myrow) * NF + f0);
        xbuf[1][0][myrow] = v1.x; xbuf[1][1][myrow] = v1.y;
        xbuf[1][2][myrow] = v1.z; xbuf[1][3][myrow] = v1.w;
    }
    __syncthreads();                             // slabs 0,1 + lds_w2 ready

    const float* wbase = lds_w2[wave];

    // h1 for row slab 0 (steady-state: h1c holds row `it`, consumed while
    // being overwritten with row `it+1`)
    float h1c[H1];
    {
        const float xv = xbuf[0][wave][lane];
        #pragma unroll
        for (int h = 0; h < H1; ++h)
            h1c[h] = elu_f(fmaf(xv, w1v[h], s_b1[h]));
    }

    int cur = 1;                                 // xbuf holding slab it+1
    int zb  = 0;

    #pragma unroll 1
    for (int it = 0; it < ITERS; ++it) {
        // 1) issue coalesced load of slab it+2 into regs
        float4 xnn;
        if (io) {
            int nit = it + 2; if (nit > ITERS - 1) nit = ITERS - 1;
            xnn = *reinterpret_cast<const float4*>(
                x + (size_t)(rowBase + nit * 64 + myrow) * NF + f0);
        }

        // 2) x for row it+1 (staged last iter, synced)
        const float xn = xbuf[cur][wave][lane];

        // 3) INTERLEAVED: consume h1c[h] (row it, FMA pipe) while overwriting
        //    it with row it+1's ELU (trans pipe). 1 exp : 8 fma per h.
        float acc[H2];
        #pragma unroll
        for (int k = 0; k < H2; ++k) acc[k] = b2v[k];

        #pragma unroll
        for (int h = 0; h < 8; ++h) {            // W2 rows 0..7: SGPR path
            const float hc = h1c[h];
            h1c[h] = elu_f(fmaf(xn, w1v[h], s_b1[h]));
            #pragma unroll
            for (int k = 0; k < H2; ++k)
                acc[k] = fmaf(hc, s_w2[h * H2 + k], acc[k]);
        }

        int dsoff = 0;                           // block LICM hoisting
        asm volatile("" : "+v"(dsoff));
        const float4* wp = reinterpret_cast<const float4*>(wbase + dsoff);
        #pragma unroll
        for (int h = 0; h < 4; ++h) {            // W2 rows 8..11: LDS path
            const float4 wlo = wp[2 * h];
            const float4 whi = wp[2 * h + 1];
            const float hc = h1c[8 + h];
            h1c[8 + h] = elu_f(fmaf(xn, w1v[8 + h], s_b1[8 + h]));
            acc[0] = fmaf(hc, wlo.x, acc[0]);
            acc[1] = fmaf(hc, wlo.y, acc[1]);
            acc[2] = fmaf(hc, wlo.z, acc[2]);
            acc[3] = fmaf(hc, wlo.w, acc[3]);
            acc[4] = fmaf(hc, whi.x, acc[4]);
            acc[5] = fmaf(hc, whi.y, acc[5]);
            acc[6] = fmaf(hc, whi.z, acc[6]);
            acc[7] = fmaf(hc, whi.w, acc[7]);
        }

        #pragma unroll
        for (int h = 0; h < 4; ++h) {            // W2 rows 12..15: VGPR path
            const float hc = h1c[12 + h];
            h1c[12 + h] = elu_f(fmaf(xn, w1v[12 + h], s_b1[12 + h]));
            #pragma unroll
            for (int k = 0; k < H2; ++k)
                acc[k] = fmaf(hc, w2v[h * H2 + k], acc[k]);
        }

        float z = s_b3;
        #pragma unroll
        for (int k = 0; k < H2; ++k)
            z = fmaf(elu_f(acc[k]), s_w3[k], z);

        // 4) stage z (padded, conflict-free); stage next x slab
        zbuf[zb][lane][wave] = z;
        if (io) {
            xbuf[cur ^ 1][0][myrow] = xnn.x; xbuf[cur ^ 1][1][myrow] = xnn.y;
            xbuf[cur ^ 1][2][myrow] = xnn.z; xbuf[cur ^ 1][3][myrow] = xnn.w;
        }

        __syncthreads();                         // z[zb] + x[cur^1] visible

        // 5) coalesced z store: one float4 per row
        if (io) {
            float4 zq;
            zq.x = zbuf[zb][myrow][0]; zq.y = zbuf[zb][myrow][1];
            zq.z = zbuf[zb][myrow][2]; zq.w = zbuf[zb][myrow][3];
            *reinterpret_cast<float4*>(
                z_out + (size_t)(rowBase + it * 64 + myrow) * NF + f0) = zq;
        }
        cur ^= 1; zb ^= 1;
    }
}

// Memory-bound epilogue: w = softplus(theta); y[row] = dot(z[row,:], w) + bias.
#define NT2 256
#define ROWS2 64
__global__ __launch_bounds__(NT2, 4)
void y_kernel(const float* __restrict__ z, const float* __restrict__ theta,
              const float* __restrict__ bias, float* __restrict__ y_out,
              float* __restrict__ w_out) {
    __shared__ __align__(16) float wls[NF];
    const int tid = threadIdx.x;
    {
        const float th = theta[tid];
        const float w  = logf(1.0f + __expf(th));
        wls[tid] = w;
        if (blockIdx.x == 0) w_out[tid] = w;
    }
    __syncthreads();
    const int wave = tid >> 6, lane = tid & 63;
    const float4 w4 = reinterpret_cast<const float4*>(wls)[lane];
    const float biasv = bias[0];
    #pragma unroll 1
    for (int r = 0; r < ROWS2 / 4; ++r) {          // 16 rows per wave
        const int row = blockIdx.x * ROWS2 + wave * (ROWS2 / 4) + r;
        const float4 zv = reinterpret_cast<const float4*>(z + row * NF)[lane];
        float s = zv.x * w4.x + zv.y * w4.y + zv.z * w4.z + zv.w * w4.w;
        #pragma unroll
        for (int o = 32; o > 0; o >>= 1) s += __shfl_down(s, o, 64);
        if (lane == 0) y_out[row] = s + biasv;
    }
}

extern "C" void kernel_launch(void* const* d_in, const int* in_sizes, int n_in,
                              void* d_out, int out_size, void* d_ws, size_t ws_size,
                              hipStream_t stream) {
    const float* x     = (const float*)d_in[0];
    const float* W1    = (const float*)d_in[1];
    const float* b1    = (const float*)d_in[2];
    const float* W2    = (const float*)d_in[3];
    const float* b2    = (const float*)d_in[4];
    const float* W3    = (const float*)d_in[5];
    const float* b3    = (const float*)d_in[6];
    const float* theta = (const float*)d_in[7];
    const float* bias  = (const float*)d_in[8];

    float* y_out = (float*)d_out;                  // [32768]
    float* w_out = y_out + NB;                     // [256]
    float* z_out = w_out + NF;                     // [32768*256]

    dim3 grid1(NB / ROWS_PER_BLOCK, NF / FPB);     // 32 x 64
    z_kernel<<<grid1, NT, 0, stream>>>(x, W1, b1, W2, b2, W3, b3, z_out);
    y_kernel<<<NB / ROWS2, NT2, 0, stream>>>(z_out, theta, bias, y_out, w_out);
}

// Round 14
// 162.351 us; speedup vs baseline: 1.4727x; 1.4727x over previous
//
#include <hip/hip_runtime.h>

#define NB 32768
#define NF 256
#define H1 16
#define H2 8
#define ROWS_PER_BLOCK 1024
#define ITERS (ROWS_PER_BLOCK / 64)   // 16 (one row per lane per iter)
#define FPB 4                         // features (waves) per block
#define NT (FPB * 64)                 // 256 threads

__device__ __forceinline__ float elu_f(float v) {
    return v > 0.0f ? v : (__expf(v) - 1.0f);
}
// force a wave-uniform float into an SGPR
__device__ __forceinline__ float rfl(float v) {
    return __int_as_float(__builtin_amdgcn_readfirstlane(__float_as_int(v)));
}

// R9 skeleton (scattered x/z, W2 rows 0-7 SGPR + rows 8-15 LDS, no barriers
// in the loop) + CROSS-ROW h1 PIPELINE, register-engineered to NOT spill:
// moving ALL of W2's high half to LDS frees 32 VGPRs, so per-lane demand is
// ~60 vs a 102 budget at launch_bounds(256,5) -- cushion ~42, the largest of
// any pipelined attempt (R13 spilled at cushion ~10; allocator needs slack).
// Pipeline: iter `it` consumes h1c[] (row it, ready in regs -> FMAs issue
// with zero latency) while overwriting each slot with row it+1's ELU (exp
// dependency shadows covered by the ready FMAs).
__global__ __launch_bounds__(NT, 5)
void z_kernel(const float* __restrict__ x,  const float* __restrict__ W1,
              const float* __restrict__ b1, const float* __restrict__ W2,
              const float* __restrict__ b2, const float* __restrict__ W3,
              const float* __restrict__ b3, float* __restrict__ z_out) {
    const int wave = threadIdx.x >> 6;
    const int lane = threadIdx.x & 63;
    const int f    = blockIdx.y * FPB + wave;
    const int rowBase = blockIdx.x * ROWS_PER_BLOCK;

    __shared__ float lds_w2[FPB][64];        // W2 rows 8..15 per feature

    // ---- stage W2 rows 8..15 into LDS (16 lanes x float4) ----
    if (lane < 16) {
        const float4 v = reinterpret_cast<const float4*>(W2 + f * H1 * H2 + 64)[lane];
        reinterpret_cast<float4*>(lds_w2[wave])[lane] = v;
    }

    // ---- W2 rows 0..7 -> SGPR ----
    float s_w2[8 * H2];
    {
        const float4* p = reinterpret_cast<const float4*>(W2 + f * H1 * H2);
        #pragma unroll
        for (int i = 0; i < 16; ++i) {
            float4 v = p[i];
            s_w2[4*i]   = rfl(v.x); s_w2[4*i+1] = rfl(v.y);
            s_w2[4*i+2] = rfl(v.z); s_w2[4*i+3] = rfl(v.w);
        }
    }
    // ---- W1 -> per-lane VGPR, b1 -> SGPR ----
    float w1v[H1], s_b1[H1];
    {
        const float4* pw = reinterpret_cast<const float4*>(W1 + f * H1);
        const float4* pb = reinterpret_cast<const float4*>(b1 + f * H1);
        #pragma unroll
        for (int i = 0; i < 4; ++i) {
            float4 v = pw[i];
            w1v[4*i] = v.x; w1v[4*i+1] = v.y; w1v[4*i+2] = v.z; w1v[4*i+3] = v.w;
        }
        #pragma unroll
        for (int i = 0; i < 4; ++i) {
            float4 v = pb[i];
            s_b1[4*i]   = rfl(v.x); s_b1[4*i+1] = rfl(v.y);
            s_b1[4*i+2] = rfl(v.z); s_b1[4*i+3] = rfl(v.w);
        }
    }
    // ---- b2 -> per-lane VGPR; W3, b3 -> SGPR ----
    float b2v[H2];
    {
        const float4* p = reinterpret_cast<const float4*>(b2 + f * H2);
        float4 v0 = p[0], v1 = p[1];
        b2v[0]=v0.x; b2v[1]=v0.y; b2v[2]=v0.z; b2v[3]=v0.w;
        b2v[4]=v1.x; b2v[5]=v1.y; b2v[6]=v1.z; b2v[7]=v1.w;
    }
    float s_w3[H2];
    {
        const float4* p = reinterpret_cast<const float4*>(W3 + f * H2);
        float4 v0 = p[0], v1 = p[1];
        s_w3[0]=rfl(v0.x); s_w3[1]=rfl(v0.y); s_w3[2]=rfl(v0.z); s_w3[3]=rfl(v0.w);
        s_w3[4]=rfl(v1.x); s_w3[5]=rfl(v1.y); s_w3[6]=rfl(v1.z); s_w3[7]=rfl(v1.w);
    }
    const float s_b3 = rfl(b3[f]);

    __syncthreads();                          // LDS W2 ready

    const float* wbase = lds_w2[wave];

    // rolling x chain: xn = x[row it+1], xnn = x[row it+2]
    const int off0 = (rowBase + lane) * NF + f;
    float h1c[H1];
    {
        const float xv = x[off0];             // row 0
        #pragma unroll
        for (int h = 0; h < H1; ++h)
            h1c[h] = elu_f(fmaf(xv, w1v[h], s_b1[h]));
    }
    float xn  = x[off0 + 64 * NF];            // row 1 (ITERS >= 2)
    int off = off0;

    #pragma unroll 1
    for (int it = 0; it < ITERS; ++it) {
        // prefetch x for row it+2
        const int off2 = off + 2 * 64 * NF;
        const float xnn = x[(it + 2 < ITERS) ? off2 : off];

        float acc[H2];
        #pragma unroll
        for (int k = 0; k < H2; ++k) acc[k] = b2v[k];

        // ---- W2 rows 0..7: SGPR path; consume h1c (row it), refill row it+1
        #pragma unroll
        for (int h = 0; h < 8; ++h) {
            const float hc = h1c[h];
            h1c[h] = elu_f(fmaf(xn, w1v[h], s_b1[h]));
            #pragma unroll
            for (int k = 0; k < H2; ++k)
                acc[k] = fmaf(hc, s_w2[h * H2 + k], acc[k]);
        }

        // ---- W2 rows 8..15: LDS broadcast path ----
        int dsoff = 0;                        // block LICM hoisting
        asm volatile("" : "+v"(dsoff));
        const float4* wp = reinterpret_cast<const float4*>(wbase + dsoff);
        #pragma unroll
        for (int h = 0; h < 8; ++h) {
            const float4 wlo = wp[2 * h];
            const float4 whi = wp[2 * h + 1];
            const float hc = h1c[8 + h];
            h1c[8 + h] = elu_f(fmaf(xn, w1v[8 + h], s_b1[8 + h]));
            acc[0] = fmaf(hc, wlo.x, acc[0]);
            acc[1] = fmaf(hc, wlo.y, acc[1]);
            acc[2] = fmaf(hc, wlo.z, acc[2]);
            acc[3] = fmaf(hc, wlo.w, acc[3]);
            acc[4] = fmaf(hc, whi.x, acc[4]);
            acc[5] = fmaf(hc, whi.y, acc[5]);
            acc[6] = fmaf(hc, whi.z, acc[6]);
            acc[7] = fmaf(hc, whi.w, acc[7]);
        }

        float z = s_b3;
        #pragma unroll
        for (int k = 0; k < H2; ++k)
            z = fmaf(elu_f(acc[k]), s_w3[k], z);

        z_out[off] = z;                       // row it
        off += 64 * NF; xn = xnn;
    }
}

// Memory-bound epilogue: w = softplus(theta); y[row] = dot(z[row,:], w) + bias.
#define NT2 256
#define ROWS2 64
__global__ __launch_bounds__(NT2, 4)
void y_kernel(const float* __restrict__ z, const float* __restrict__ theta,
              const float* __restrict__ bias, float* __restrict__ y_out,
              float* __restrict__ w_out) {
    __shared__ __align__(16) float wls[NF];
    const int tid = threadIdx.x;
    {
        const float th = theta[tid];
        const float w  = logf(1.0f + __expf(th));
        wls[tid] = w;
        if (blockIdx.x == 0) w_out[tid] = w;
    }
    __syncthreads();
    const int wave = tid >> 6, lane = tid & 63;
    const float4 w4 = reinterpret_cast<const float4*>(wls)[lane];
    const float biasv = bias[0];
    #pragma unroll 1
    for (int r = 0; r < ROWS2 / 4; ++r) {          // 16 rows per wave
        const int row = blockIdx.x * ROWS2 + wave * (ROWS2 / 4) + r;
        const float4 zv = reinterpret_cast<const float4*>(z + row * NF)[lane];
        float s = zv.x * w4.x + zv.y * w4.y + zv.z * w4.z + zv.w * w4.w;
        #pragma unroll
        for (int o = 32; o > 0; o >>= 1) s += __shfl_down(s, o, 64);
        if (lane == 0) y_out[row] = s + biasv;
    }
}

extern "C" void kernel_launch(void* const* d_in, const int* in_sizes, int n_in,
                              void* d_out, int out_size, void* d_ws, size_t ws_size,
                              hipStream_t stream) {
    const float* x     = (const float*)d_in[0];
    const float* W1    = (const float*)d_in[1];
    const float* b1    = (const float*)d_in[2];
    const float* W2    = (const float*)d_in[3];
    const float* b2    = (const float*)d_in[4];
    const float* W3    = (const float*)d_in[5];
    const float* b3    = (const float*)d_in[6];
    const float* theta = (const float*)d_in[7];
    const float* bias  = (const float*)d_in[8];

    float* y_out = (float*)d_out;                  // [32768]
    float* w_out = y_out + NB;                     // [256]
    float* z_out = w_out + NF;                     // [32768*256]

    dim3 grid1(NB / ROWS_PER_BLOCK, NF / FPB);     // 32 x 64
    z_kernel<<<grid1, NT, 0, stream>>>(x, W1, b1, W2, b2, W3, b3, z_out);
    y_kernel<<<NB / ROWS2, NT2, 0, stream>>>(z_out, theta, bias, y_out, w_out);
}